// Round 18
// baseline (295.526 us; speedup 1.0000x reference)
//
#include <hip/hip_runtime.h>

#define NT 256

typedef __attribute__((ext_vector_type(8))) short short8b;
typedef __attribute__((ext_vector_type(4))) float f32x4;

__device__ inline unsigned short f2bf(float f) {
    unsigned u = __float_as_uint(f);
    unsigned r = (u + 0x7fffu + ((u >> 16) & 1u)) >> 16;
    return (unsigned short)r;
}
__device__ inline float bf2f(unsigned short h) {
    return __uint_as_float(((unsigned)h) << 16);
}

// ---------------- workspace layout (float offsets) ----------------
// [0..8192) floats: spw_hi u16[8192] then spw_lo u16[8192], layout [h][c]
#define WS_SC1     8192     // [128] bn1 scale
#define WS_SH1     8320     // [128] bn1 shift (conv_b folded)
#define WS_SC2     8448     // [128] bn2 scale
#define WS_SH2     8576     // [128] bn2 shift
#define WS_LIWT    8704     // [128][64]  li_wT[j][o] = li_w[o][j]
#define WS_TW1T    16896    // [150][64]  tda_w1T[i][o]
#define WS_TW2T    26496    // [64][32]   tda_w2T[j][o2]
#define WS_CW1T    28544    // [672][128] cls_w1T[j][c]
#define WS_TOTAL   114560   // end of transposed tables
#define WS_WG      114560   // [10] Wg window constants
#define WS_WBASE   114688   // [B][10][128] window features

// ---------------- prep: transposes + BN folds + Wg + sp_w bf16 hi/lo ---------
__global__ void prep_kernel(
    const float* __restrict__ conv_b, const float* __restrict__ bn1_g,
    const float* __restrict__ bn1_b,  const float* __restrict__ bn1_m,
    const float* __restrict__ bn1_v,  const float* __restrict__ sp_w,
    const float* __restrict__ li_w,   const float* __restrict__ tda_w1,
    const float* __restrict__ tda_w2, const float* __restrict__ cls_w1,
    const float* __restrict__ bn2_g,  const float* __restrict__ bn2_b,
    const float* __restrict__ bn2_m,  const float* __restrict__ bn2_v,
    float* __restrict__ ws)
{
    int i = blockIdx.x * NT + threadIdx.x;
    if (i > WS_TOTAL) return;
    if (i == WS_TOTAL) {                    // Wg[10]: data-independent li-bias windows
        float g = 0.f, sE = 0.f, sL = 0.f; int w = 0;
        for (int t = 0; t < 320; ++t) {
            g = fmaf(0.9f, g, 1.f);
            int pos = t & 31;
            if (pos < 16) sE += g; else sL += g;
            if (pos == 31) { ws[WS_WG + w] = sL - sE; ++w; sE = 0.f; sL = 0.f; }
        }
        return;
    }
    if (i < 8192) {                         // sp_w bf16 hi/lo split ([h][c])
        unsigned short* ws16 = (unsigned short*)ws;
        float v = sp_w[i];
        unsigned short hv = f2bf(v);
        ws16[i] = hv;
        ws16[8192 + i] = f2bf(v - bf2f(hv));
    } else if (i < WS_SH1) {                // bn1 scale
        int c = i - WS_SC1;
        float vv = bn1_v[c] + 1e-5f;
        ws[i] = (float)((double)bn1_g[c] / sqrt((double)vv));
    } else if (i < WS_SC2) {                // bn1 shift
        int c = i - WS_SH1;
        float vv = bn1_v[c] + 1e-5f;
        double s = (double)bn1_g[c] / sqrt((double)vv);
        ws[i] = (float)(((double)conv_b[c] - (double)bn1_m[c])*s + (double)bn1_b[c]);
    } else if (i < WS_SH2) {                // bn2 scale
        int c = i - WS_SC2;
        float vv = bn2_v[c] + 1e-5f;
        ws[i] = (float)((double)bn2_g[c] / sqrt((double)vv));
    } else if (i < WS_LIWT) {               // bn2 shift
        int c = i - WS_SH2;
        float vv = bn2_v[c] + 1e-5f;
        double s = (double)bn2_g[c] / sqrt((double)vv);
        ws[i] = (float)((double)bn2_b[c] - (double)bn2_m[c]*s);
    } else if (i < WS_TW1T) {               // li_wT
        int t = i - WS_LIWT; int j = t >> 6, o = t & 63;
        ws[i] = li_w[o*128 + j];
    } else if (i < WS_TW2T) {               // tda_w1T
        int t = i - WS_TW1T; int r = t >> 6, o = t & 63;
        ws[i] = tda_w1[o*150 + r];
    } else if (i < WS_CW1T) {               // tda_w2T
        int t = i - WS_TW2T; int j = t >> 5, o = t & 31;
        ws[i] = tda_w2[o*64 + j];
    } else {                                // cls_w1T
        int t = i - WS_CW1T; int j = t >> 7, c = t & 127;
        ws[i] = cls_w1[c*672 + j];
    }
}

// ---------------- fused kernel: conv + bf16x4 MFMA proj + LIF scan -----------
// r15 structure (one block per b, 5 chunks, 2 barriers/chunk, cur in LDS),
// projection moved to matrix cores. Per chunk:
//   A: [x prefetch] ; B-frags from ylds ; 64 MFMA -> cur_lds ; barrier
//   B: wave0 scans 64 steps (state in regs, W -> ws); all waves conv next
//      chunk -> ylds (bf16 hi/lo); barrier
__launch_bounds__(NT, 3)
__global__ void fused_kernel(
    const float* __restrict__ x, const float* __restrict__ conv_w,
    const float* __restrict__ sp_b, const float* __restrict__ ws,
    float* __restrict__ wfeat)
{
    __shared__ unsigned short ylds[2][64*128];   // hi/lo planes, swizzled, 32 KB
    __shared__ float cur_lds[64*64];             // 16.4 KB, t*64 + (h ^ ((t&15)<<2))

    const int tid  = threadIdx.x;
    const int b    = blockIdx.x;
    const int ic   = tid & 63;
    const int tg   = tid >> 6;
    const int lane = tid & 63;
    const int wid  = tid >> 6;
    const int kg   = lane >> 4;          // MFMA k quarter-group
    const int ha   = lane & 15;          // MFMA A row within m-tile
    const int tl   = tg*16 + ha;         // this wave's t column (chunk-local)

    // ---- per-block constants ----
    float w0[15], w1[15];
    #pragma unroll
    for (int k = 0; k < 15; ++k) {
        w0[k] = conv_w[(2*ic)*15 + k];
        w1[k] = conv_w[(2*ic + 1)*15 + k];
    }
    const float sA = ws[WS_SC1 + 2*ic],     hA = ws[WS_SH1 + 2*ic];
    const float sB = ws[WS_SC1 + 2*ic + 1], hB = ws[WS_SH1 + 2*ic + 1];
    // sp_b folded into MFMA C-init: lane's D rows are h = mt*16 + kg*4 + r
    f32x4 spb4[4];
    #pragma unroll
    for (int mt = 0; mt < 4; ++mt)
        spb4[mt] = *reinterpret_cast<const f32x4*>(sp_b + mt*16 + kg*4);

    const unsigned short* wsh = (const unsigned short*)ws;  // spw_hi [64][128]
    const unsigned short* wsl = wsh + 8192;                 // spw_lo
    const float* xb = x + (size_t)b * 20480 + ic;
    float* Wb = wfeat + (size_t)b * 1280;

    // ---- scan state (wave 0, lane = h) ----
    float mf = 0.f, ms = 0.f, rlo = 0.f, rhi = 0.f;

    // ---- prologue: chunk 0 x + conv -> ylds ----
    float xr0[30], xr1[30];
    #pragma unroll
    for (int r = 0; r < 30; ++r) {
        int t = tg*16 - 7 + r;
        xr0[r] = (t >= 0) ? xb[(size_t)t * 64] : 0.f;
    }
    #pragma unroll
    for (int j = 0; j < 16; ++j) {
        float a0 = 0.f, a1 = 0.f;
        #pragma unroll
        for (int k = 0; k < 15; ++k) {
            a0 = fmaf(xr0[j + k], w0[k], a0);
            a1 = fmaf(xr0[j + k], w1[k], a1);
        }
        float y0 = fmaxf(fmaf(a0, sA, hA), 0.f);
        float y1 = fmaxf(fmaf(a1, sB, hB), 0.f);
        int tt = tg*16 + j;
        unsigned off = (unsigned)(tt*256) + (((unsigned)(ic*4)) ^ ((unsigned)((tt & 7) << 4)));
        unsigned short y0h = f2bf(y0), y1h = f2bf(y1);
        unsigned short y0l = f2bf(y0 - bf2f(y0h)), y1l = f2bf(y1 - bf2f(y1h));
        *(unsigned*)((char*)&ylds[0][0] + off) = (unsigned)y0h | ((unsigned)y1h << 16);
        *(unsigned*)((char*)&ylds[1][0] + off) = (unsigned)y0l | ((unsigned)y1l << 16);
    }
    __syncthreads();

    #pragma unroll
    for (int chk = 0; chk < 5; ++chk) {
        float* xn = (chk & 1) ? xr0 : xr1;   // static after full unroll

        // ---- issue next chunk's x loads (fly under MFMA phase) ----
        if (chk < 4) {
            const int tbase = (chk + 1)*64 + tg*16 - 7;   // >= 57: only upper guard
            if (tbase + 29 < 320) {
                #pragma unroll
                for (int r = 0; r < 30; ++r)
                    xn[r] = xb[(size_t)(tbase + r) * 64];
            } else {
                #pragma unroll
                for (int r = 0; r < 30; ++r) {
                    int t = tbase + r;
                    xn[r] = (t < 320) ? xb[(size_t)t * 64] : 0.f;
                }
            }
        }

        // ---- projection via MFMA: cur[h][t=tl] = spb[h] + sum_c y[t][c]*w[h][c] ----
        {
            short8b Bh[4], Bl[4];
            const unsigned tswz = (unsigned)((tl & 7) << 4);
            #pragma unroll
            for (int ks = 0; ks < 4; ++ks) {
                unsigned off = (unsigned)(tl*256) + (((unsigned)(ks*64 + kg*16)) ^ tswz);
                Bh[ks] = *(const short8b*)((const char*)&ylds[0][0] + off);
                Bl[ks] = *(const short8b*)((const char*)&ylds[1][0] + off);
            }
            #pragma unroll
            for (int mt = 0; mt < 4; ++mt) {
                const unsigned short* ap = wsh + (mt*16 + ha)*128;
                const unsigned short* lp = wsl + (mt*16 + ha)*128;
                f32x4 acc = spb4[mt];
                #pragma unroll
                for (int ks = 0; ks < 4; ++ks) {
                    short8b Ah = *(const short8b*)(ap + ks*32 + kg*8);
                    short8b Al = *(const short8b*)(lp + ks*32 + kg*8);
                    acc = __builtin_amdgcn_mfma_f32_16x16x32_bf16(Ah, Bh[ks], acc, 0, 0, 0);
                    acc = __builtin_amdgcn_mfma_f32_16x16x32_bf16(Ah, Bl[ks], acc, 0, 0, 0);
                    acc = __builtin_amdgcn_mfma_f32_16x16x32_bf16(Al, Bh[ks], acc, 0, 0, 0);
                    acc = __builtin_amdgcn_mfma_f32_16x16x32_bf16(Al, Bl[ks], acc, 0, 0, 0);
                }
                // D: row (h) = mt*16 + kg*4 + r, col (t) = tl; swizzled float4 store
                const int hb = mt*16 + kg*4;
                *reinterpret_cast<f32x4*>(
                    &cur_lds[tl*64 + (hb ^ ((tl & 15) << 2))]) = acc;
            }
        }
        __syncthreads();

        // ---- wave 0: LIF scan of this chunk; all waves: conv of next chunk ----
        if (wid == 0) {
            float sE_lo = 0.f, sE_hi = 0.f;
            #pragma unroll
            for (int gq = 0; gq < 4; ++gq) {
                float v[16];
                #pragma unroll
                for (int q = 0; q < 16; ++q) {
                    int t = gq*16 + q;
                    v[q] = cur_lds[t*64 + (lane ^ ((t & 15) << 2))];
                }
                float slo = 0.f, shi = 0.f;
                #pragma unroll
                for (int q = 0; q < 16; ++q) {
                    float c = v[q];
                    mf = fmaf(0.5f, mf, c);
                    bool sf = mf >= 0.5f;
                    ms = fmaf(0.9f, ms, c);
                    bool ss = ms >= 1.0f;
                    mf = sf ? 0.f : mf;
                    ms = ss ? 0.f : ms;
                    rlo = fmaf(0.9f, rlo, sf ? 1.f : 0.f);
                    rhi = fmaf(0.9f, rhi, ss ? 1.f : 0.f);
                    slo += rlo; shi += rhi;
                }
                if ((gq & 1) == 0) {
                    sE_lo = slo; sE_hi = shi;
                } else {
                    int wdx = chk*2 + (gq >> 1);
                    Wb[wdx*128 + lane]      = slo - sE_lo;
                    Wb[wdx*128 + 64 + lane] = shi - sE_hi;
                }
            }
        }
        if (chk < 4) {
            #pragma unroll
            for (int j = 0; j < 16; ++j) {
                float a0 = 0.f, a1 = 0.f;
                #pragma unroll
                for (int k = 0; k < 15; ++k) {
                    a0 = fmaf(xn[j + k], w0[k], a0);
                    a1 = fmaf(xn[j + k], w1[k], a1);
                }
                float y0 = fmaxf(fmaf(a0, sA, hA), 0.f);
                float y1 = fmaxf(fmaf(a1, sB, hB), 0.f);
                int tt = tg*16 + j;
                unsigned off = (unsigned)(tt*256) + (((unsigned)(ic*4)) ^ ((unsigned)((tt & 7) << 4)));
                unsigned short y0h = f2bf(y0), y1h = f2bf(y1);
                unsigned short y0l = f2bf(y0 - bf2f(y0h)), y1l = f2bf(y1 - bf2f(y1h));
                *(unsigned*)((char*)&ylds[0][0] + off) = (unsigned)y0h | ((unsigned)y1h << 16);
                *(unsigned*)((char*)&ylds[1][0] + off) = (unsigned)y0l | ((unsigned)y1l << 16);
            }
        }
        __syncthreads();
    }
}

// ---------------- kernel C: classifier epilogue, one block per b ----------------
__global__ void epilogue_kernel(
    const float* __restrict__ tda,    const float* __restrict__ li_b,
    const float* __restrict__ tda_b1, const float* __restrict__ tda_b2,
    const float* __restrict__ cls_b1, const float* __restrict__ cls_w2,
    const float* __restrict__ cls_b2, const float* __restrict__ ws,
    const float* __restrict__ W,      float* __restrict__ out)
{
    __shared__ float Wl[1280];
    __shared__ float t1[64], tf[32], dp[640], h1[128];
    const int b = blockIdx.x, tid = threadIdx.x;

    for (int i = tid; i < 1280; i += NT)
        Wl[i] = W[(size_t)b*1280 + i];
    __syncthreads();

    const float* __restrict__ liwT = ws + WS_LIWT;
    const float* __restrict__ tw1T = ws + WS_TW1T;
    const float* __restrict__ tw2T = ws + WS_TW2T;
    const float* __restrict__ cw1T = ws + WS_CW1T;
    const float* tdab = tda + b*150;

    if (tid < 64) {                     // tda layer 1
        float acc = tda_b1[tid];
        for (int i2 = 0; i2 < 150; ++i2)
            acc = fmaf(tdab[i2], tw1T[i2*64 + tid], acc);
        t1[tid] = fmaxf(acc, 0.f);
    }
    __syncthreads();
    if (tid < 32) {                     // tda layer 2
        float acc = tda_b2[tid];
        #pragma unroll 8
        for (int j = 0; j < 64; ++j)
            acc = fmaf(t1[j], tw2T[j*32 + tid], acc);
        tf[tid] = fmaxf(acc, 0.f);
    }
    // dp_feat = (1/16) * (li_w @ W + li_b * Wg)
    {
        int o = tid & 63;
        for (int w = tid >> 6; w < 10; w += 4) {
            float acc = li_b[o] * ws[WS_WG + w];
            #pragma unroll 4
            for (int j = 0; j < 128; ++j)
                acc = fmaf(Wl[w*128 + j], liwT[j*64 + o], acc);
            dp[w*64 + o] = 0.0625f * acc;
        }
    }
    __syncthreads();
    if (tid < 128) {                    // classifier layer 1 + BN2 + ReLU
        float acc = cls_b1[tid];
        for (int j = 0; j < 640; ++j)
            acc = fmaf(dp[j], cw1T[j*128 + tid], acc);
        #pragma unroll 4
        for (int j = 0; j < 32; ++j)
            acc = fmaf(tf[j], cw1T[(640 + j)*128 + tid], acc);
        float s2 = ws[WS_SC2 + tid], sh2 = ws[WS_SH2 + tid];
        h1[tid] = fmaxf(fmaf(acc, s2, sh2), 0.f);
    }
    __syncthreads();
    if (tid < 4) {                      // classifier layer 2
        float acc = cls_b2[tid];
        for (int c = 0; c < 128; ++c)
            acc = fmaf(h1[c], cls_w2[tid*128 + c], acc);
        out[b*4 + tid] = acc;
    }
}

extern "C" void kernel_launch(void* const* d_in, const int* in_sizes, int n_in,
                              void* d_out, int out_size, void* d_ws, size_t ws_size,
                              hipStream_t stream) {
    const float* x      = (const float*)d_in[0];
    const float* tda    = (const float*)d_in[1];
    const float* conv_w = (const float*)d_in[2];
    const float* conv_b = (const float*)d_in[3];
    const float* bn1_g  = (const float*)d_in[4];
    const float* bn1_b  = (const float*)d_in[5];
    const float* bn1_m  = (const float*)d_in[6];
    const float* bn1_v  = (const float*)d_in[7];
    const float* sp_w   = (const float*)d_in[8];
    const float* sp_b   = (const float*)d_in[9];
    const float* li_w   = (const float*)d_in[10];
    const float* li_b   = (const float*)d_in[11];
    const float* tda_w1 = (const float*)d_in[12];
    const float* tda_b1 = (const float*)d_in[13];
    const float* tda_w2 = (const float*)d_in[14];
    const float* tda_b2 = (const float*)d_in[15];
    const float* cls_w1 = (const float*)d_in[16];
    const float* cls_b1 = (const float*)d_in[17];
    const float* bn2_g  = (const float*)d_in[18];
    const float* bn2_b  = (const float*)d_in[19];
    const float* bn2_m  = (const float*)d_in[20];
    const float* bn2_v  = (const float*)d_in[21];
    const float* cls_w2 = (const float*)d_in[22];
    const float* cls_b2 = (const float*)d_in[23];
    float* ws  = (float*)d_ws;
    float* out = (float*)d_out;

    const int B = in_sizes[0] / (320 * 64);   // 2048

    prep_kernel<<<(WS_TOTAL + 1 + NT - 1)/NT, NT, 0, stream>>>(
        conv_b, bn1_g, bn1_b, bn1_m, bn1_v, sp_w,
        li_w, tda_w1, tda_w2, cls_w1,
        bn2_g, bn2_b, bn2_m, bn2_v, ws);

    fused_kernel<<<B, NT, 0, stream>>>(
        x, conv_w, sp_b, ws, ws + WS_WBASE);

    epilogue_kernel<<<B, NT, 0, stream>>>(
        tda, li_b, tda_b1, tda_b2, cls_b1, cls_w2, cls_b2,
        ws, ws + WS_WBASE, out);
}